// Round 1
// baseline (1445.395 us; speedup 1.0000x reference)
//
#include <hip/hip_runtime.h>
#include <hip/hip_bf16.h>

#define NXg 432
#define NYg 496
#define Bg  4
#define Hg  248
#define Wg  216
#define HWg (Hg*Wg)          /* 53568 */
#define CINg 384
#define NDFg 16
#define KS  15
#define RAD 7

// ---- workspace layout (float offsets) ----
// hist : 0          .. 857088
// tmpy : 857088     .. 1714176
// blur : 1714176    .. 2571264
// dmr  : 2571264    .. 2785536
// tmp1 : 2785536    .. 4499712   (B*8*HW)
// tmp2 : 4499712    .. 7928064   (B*16*HW)
// maxb : 7928064    (4 uints)
// stats1 (16 dbl = 32 f): 7928072
// stats2 (32 dbl = 64 f): 7928104
// bnp1 (16 f): 7928168
// bnp2 (32 f): 7928184
#define OFF_HIST  0
#define OFF_TMPY  857088
#define OFF_BLUR  1714176
#define OFF_DMR   2571264
#define OFF_TMP1  2785536
#define OFF_TMP2  4499712
#define OFF_MAXB  7928064
#define OFF_ST1   7928072
#define OFF_ST2   7928104
#define OFF_BNP1  7928168
#define OFF_BNP2  7928184

__device__ __forceinline__ void gauss_w(float* g) {
    float s = 0.f;
    #pragma unroll
    for (int i = 0; i < KS; ++i) {
        float c = (float)(i - RAD);
        float v = expf(-c * c / (2.0f * 6.25f * 6.25f));
        g[i] = v; s += v;
    }
    #pragma unroll
    for (int i = 0; i < KS; ++i) g[i] /= s;
}

__global__ __launch_bounds__(256) void k_scatter(const float* __restrict__ pts, int n,
                                                 float* __restrict__ hist) {
    int i = blockIdx.x * blockDim.x + threadIdx.x;
    int stride = gridDim.x * blockDim.x;
    for (; i < n; i += stride) {
        const float* p = pts + (size_t)i * 5;
        int b  = (int)p[0];
        int xi = (int)((p[1] - 0.0f) / 0.16f);
        int yi = (int)((p[2] - (-39.68f)) / 0.16f);
        xi = min(max(xi, 0), NXg - 1);
        yi = min(max(yi, 0), NYg - 1);
        atomicAdd(&hist[(b * NYg + yi) * NXg + xi], 1.0f);
    }
}

__global__ __launch_bounds__(256) void k_blur_y(const float* __restrict__ src,
                                                 float* __restrict__ dst) {
    float g[KS]; gauss_w(g);
    int idx = blockIdx.x * 256 + threadIdx.x;        // total B*NY*NX (exact)
    int x = idx % NXg; int t = idx / NXg;
    int y = t % NYg;   int b = t / NYg;
    float acc = 0.f;
    #pragma unroll
    for (int k = 0; k < KS; ++k) {
        int yy = y + k - RAD;
        if (yy >= 0 && yy < NYg) acc += g[k] * src[(b * NYg + yy) * NXg + x];
    }
    dst[idx] = acc;
}

__global__ __launch_bounds__(256) void k_blur_x_max(const float* __restrict__ src,
                                                     float* __restrict__ dst,
                                                     unsigned int* __restrict__ maxb) {
    float g[KS]; gauss_w(g);
    int idx = blockIdx.x * 256 + threadIdx.x;
    int x = idx % NXg; int t = idx / NXg;
    int y = t % NYg;   int b = t / NYg;
    float acc = 0.f;
    #pragma unroll
    for (int k = 0; k < KS; ++k) {
        int xx = x + k - RAD;
        if (xx >= 0 && xx < NXg) acc += g[k] * src[(b * NYg + y) * NXg + xx];
    }
    dst[idx] = acc;
    // block max (each block lies within one batch: NY*NX = 214272 = 837*256)
    __shared__ float red[256];
    red[threadIdx.x] = acc;
    __syncthreads();
    for (int o = 128; o > 0; o >>= 1) {
        if (threadIdx.x < o) red[threadIdx.x] = fmaxf(red[threadIdx.x], red[threadIdx.x + o]);
        __syncthreads();
    }
    if (threadIdx.x == 0) atomicMax(&maxb[b], __float_as_uint(red[0]));
}

__global__ __launch_bounds__(256) void k_resize(const float* __restrict__ blur,
                                                 const unsigned int* __restrict__ maxb,
                                                 float* __restrict__ dmr) {
    int idx = blockIdx.x * 256 + threadIdx.x;        // total B*H*W (exact)
    int ox = idx % Wg; int t = idx / Wg;
    int oy = t % Hg;   int b = t / Hg;
    const float wt[4] = {0.25f, 0.75f, 0.75f, 0.25f};
    int iy0 = 2 * oy - 1, ix0 = 2 * ox - 1;
    float wsx = 0.f;
    #pragma unroll
    for (int tx = 0; tx < 4; ++tx) { int ix = ix0 + tx; if (ix >= 0 && ix < NXg) wsx += wt[tx]; }
    float num = 0.f, wsy = 0.f;
    #pragma unroll
    for (int ty = 0; ty < 4; ++ty) {
        int iy = iy0 + ty;
        if (iy < 0 || iy >= NYg) continue;
        wsy += wt[ty];
        float row = 0.f;
        #pragma unroll
        for (int tx = 0; tx < 4; ++tx) {
            int ix = ix0 + tx;
            if (ix >= 0 && ix < NXg) row += wt[tx] * blur[(b * NYg + iy) * NXg + ix];
        }
        num += wt[ty] * row;
    }
    float v = num / (wsy * wsx);
    float m = __uint_as_float(maxb[b]);
    dmr[idx] = (m > 0.f) ? v / m : v;
}

__global__ __launch_bounds__(256) void k_conv1(const float* __restrict__ dmr,
                                                const float* __restrict__ w1,
                                                float* __restrict__ tmp1,
                                                double* __restrict__ stats1) {
    __shared__ float w[72];
    if (threadIdx.x < 72) w[threadIdx.x] = w1[threadIdx.x];
    __syncthreads();
    int idx = blockIdx.x * 256 + threadIdx.x;        // B*H*W exact
    int x = idx % Wg; int t = idx / Wg;
    int y = t % Hg;   int b = t / Hg;
    float v[9];
    #pragma unroll
    for (int ky = 0; ky < 3; ++ky)
        #pragma unroll
        for (int kx = 0; kx < 3; ++kx) {
            int yy = y + ky - 1, xx = x + kx - 1;
            v[ky * 3 + kx] = (yy >= 0 && yy < Hg && xx >= 0 && xx < Wg)
                             ? dmr[(b * Hg + yy) * Wg + xx] : 0.f;
        }
    float out[8];
    #pragma unroll
    for (int c = 0; c < 8; ++c) {
        float a = 0.f;
        #pragma unroll
        for (int j = 0; j < 9; ++j) a = fmaf(w[c * 9 + j], v[j], a);
        out[c] = a;
        tmp1[(b * 8 + c) * HWg + y * Wg + x] = a;
    }
    #pragma unroll
    for (int c = 0; c < 8; ++c) {
        double s = (double)out[c];
        double q = (double)out[c] * (double)out[c];
        for (int o = 32; o > 0; o >>= 1) { s += __shfl_down(s, o); q += __shfl_down(q, o); }
        if ((threadIdx.x & 63) == 0) {
            atomicAdd(&stats1[c], s);
            atomicAdd(&stats1[8 + c], q);
        }
    }
}

__global__ void k_fin_bn(const double* __restrict__ stats, float* __restrict__ bnp,
                         const float* __restrict__ gamma, const float* __restrict__ beta,
                         int C) {
    int c = threadIdx.x;
    if (c >= C) return;
    const double N = (double)(Bg * HWg);
    double mean = stats[c] / N;
    double var  = stats[C + c] / N - mean * mean;
    if (var < 0.0) var = 0.0;
    float sc = gamma[c] * rsqrtf((float)var + 1e-3f);
    bnp[c] = sc;
    bnp[C + c] = beta[c] - (float)mean * sc;
}

__global__ __launch_bounds__(256) void k_conv2(const float* __restrict__ tmp1,
                                                const float* __restrict__ w2,
                                                const float* __restrict__ bnp1,
                                                float* __restrict__ tmp2,
                                                double* __restrict__ stats2) {
    __shared__ float w[1152];
    __shared__ float sc[8], sh[8];
    for (int i = threadIdx.x; i < 1152; i += 256) w[i] = w2[i];
    if (threadIdx.x < 8) { sc[threadIdx.x] = bnp1[threadIdx.x]; sh[threadIdx.x] = bnp1[8 + threadIdx.x]; }
    __syncthreads();
    int idx = blockIdx.x * 256 + threadIdx.x;        // B*H*W exact
    int x = idx % Wg; int t = idx / Wg;
    int y = t % Hg;   int b = t / Hg;
    float acc[16];
    #pragma unroll
    for (int c = 0; c < 16; ++c) acc[c] = 0.f;
    #pragma unroll
    for (int ky = 0; ky < 3; ++ky) {
        int yy = y + ky - 1;
        if (yy < 0 || yy >= Hg) continue;
        #pragma unroll
        for (int kx = 0; kx < 3; ++kx) {
            int xx = x + kx - 1;
            if (xx < 0 || xx >= Wg) continue;
            float hv[8];
            int base = b * 8 * HWg + yy * Wg + xx;
            #pragma unroll
            for (int ci = 0; ci < 8; ++ci)
                hv[ci] = fmaxf(fmaf(sc[ci], tmp1[base + ci * HWg], sh[ci]), 0.f);
            #pragma unroll
            for (int co = 0; co < 16; ++co)
                #pragma unroll
                for (int ci = 0; ci < 8; ++ci)
                    acc[co] = fmaf(w[((co * 8 + ci) * 3 + ky) * 3 + kx], hv[ci], acc[co]);
        }
    }
    #pragma unroll
    for (int co = 0; co < 16; ++co)
        tmp2[(b * 16 + co) * HWg + y * Wg + x] = acc[co];
    #pragma unroll
    for (int co = 0; co < 16; ++co) {
        double s = (double)acc[co];
        double q = (double)acc[co] * (double)acc[co];
        for (int o = 32; o > 0; o >>= 1) { s += __shfl_down(s, o); q += __shfl_down(q, o); }
        if ((threadIdx.x & 63) == 0) {
            atomicAdd(&stats2[co], s);
            atomicAdd(&stats2[16 + co], q);
        }
    }
}

__global__ __launch_bounds__(256) void k_out(const float* __restrict__ spatial,
                                              const float* __restrict__ tmp2,
                                              const float* __restrict__ bnp2,
                                              float* __restrict__ out) {
    const int chw4 = (CINg + NDFg) * HWg / 4;        // 5,356,800
    const int sp4  = CINg * HWg / 4;                 // 5,142,528
    const int total4 = Bg * chw4;                    // 21,427,200
    int i = blockIdx.x * blockDim.x + threadIdx.x;
    int stride = gridDim.x * blockDim.x;
    for (; i < total4; i += stride) {
        int b = i / chw4;
        int r = i - b * chw4;
        if (r < sp4) {
            reinterpret_cast<float4*>(out)[i] =
                reinterpret_cast<const float4*>(spatial)[b * sp4 + r];
        } else {
            int r2 = r - sp4;
            int c = (r2 * 4) / HWg;
            int p = (r2 * 4) - c * HWg;
            float s = bnp2[c], t = bnp2[16 + c];
            float4 v = *reinterpret_cast<const float4*>(tmp2 + (b * 16 + c) * HWg + p);
            float4 o;
            o.x = fmaxf(fmaf(s, v.x, t), 0.f);
            o.y = fmaxf(fmaf(s, v.y, t), 0.f);
            o.z = fmaxf(fmaf(s, v.z, t), 0.f);
            o.w = fmaxf(fmaf(s, v.w, t), 0.f);
            reinterpret_cast<float4*>(out)[i] = o;
        }
    }
}

extern "C" void kernel_launch(void* const* d_in, const int* in_sizes, int n_in,
                              void* d_out, int out_size, void* d_ws, size_t ws_size,
                              hipStream_t stream) {
    const float* spatial = (const float*)d_in[0];
    const float* points  = (const float*)d_in[1];
    const float* w1      = (const float*)d_in[2];
    const float* gamma1  = (const float*)d_in[3];
    const float* beta1   = (const float*)d_in[4];
    const float* w2      = (const float*)d_in[5];
    const float* gamma2  = (const float*)d_in[6];
    const float* beta2   = (const float*)d_in[7];
    float* out = (float*)d_out;

    float* ws = (float*)d_ws;
    float* hist = ws + OFF_HIST;
    float* tmpy = ws + OFF_TMPY;
    float* blur = ws + OFF_BLUR;
    float* dmr  = ws + OFF_DMR;
    float* tmp1 = ws + OFF_TMP1;
    float* tmp2 = ws + OFF_TMP2;
    unsigned int* maxb = (unsigned int*)(ws + OFF_MAXB);
    double* stats1 = (double*)(ws + OFF_ST1);
    double* stats2 = (double*)(ws + OFF_ST2);
    float* bnp1 = ws + OFF_BNP1;
    float* bnp2 = ws + OFF_BNP2;

    int npts = in_sizes[1] / 5;

    // zero hist + (maxb, stats1, stats2) region
    hipMemsetAsync(hist, 0, (size_t)Bg * NYg * NXg * sizeof(float), stream);
    hipMemsetAsync(ws + OFF_MAXB, 0, (OFF_BNP1 - OFF_MAXB) * sizeof(float), stream);

    k_scatter<<<(npts + 255) / 256, 256, 0, stream>>>(points, npts, hist);

    const int nBlur = Bg * NYg * NXg / 256;          // 3348
    k_blur_y<<<nBlur, 256, 0, stream>>>(hist, tmpy);
    k_blur_x_max<<<nBlur, 256, 0, stream>>>(tmpy, blur, maxb);

    const int nPix = Bg * Hg * Wg / 256;             // 837
    k_resize<<<nPix, 256, 0, stream>>>(blur, maxb, dmr);
    k_conv1<<<nPix, 256, 0, stream>>>(dmr, w1, tmp1, stats1);
    k_fin_bn<<<1, 64, 0, stream>>>(stats1, bnp1, gamma1, beta1, 8);
    k_conv2<<<nPix, 256, 0, stream>>>(tmp1, w2, bnp1, tmp2, stats2);
    k_fin_bn<<<1, 64, 0, stream>>>(stats2, bnp2, gamma2, beta2, 16);

    k_out<<<2048, 256, 0, stream>>>(spatial, tmp2, bnp2, out);
}